// Round 4
// baseline (88257.727 us; speedup 1.0000x reference)
//
#include <hip/hip_runtime.h>
#include <hip/hip_cooperative_groups.h>
#include <math.h>

namespace cg = cooperative_groups;

#define T_  512
#define B_  128
#define H_  256
#define A_  18
#define G4H 1024          // 4*H
#define TB_ (T_*B_)       // 65536

// d_out layout (floats): [logits T*B*A][baseline T*B][action T*B][hT L*B*H][cT L*B*H]
#define OUT_BASE  (TB_*A_)
#define OUT_ACT   (OUT_BASE + TB_)
#define OUT_HT    (OUT_ACT + TB_)
#define OUT_CT    (OUT_HT + 2*B_*H_)

// WG tiling: 16 j-slices (16 h-units -> 64 gate rows/matrix) x 16 batch-slices (8 batches)
// 512 threads = 8 waves; wave q owns k-chunk [32q,32q+32) of each matrix; lane j = local gate row.
//
// __launch_bounds__(512, 1): R1 ran this exact kernel with (512,2) and PASSED but
// showed VGPR_Count=128 -> HIP treats arg2 as CUDA min-BLOCKS/CU (2 blocks x 8 waves
// = 16 waves/CU -> 128-VGPR cap) -> the 128-float weight fragments spilled to
// scratch -> 19.6 GB HBM traffic, 86 ms. (512,1) = 8 waves/CU -> 256-VGPR cap;
// ~230 VGPRs needed -> no spill. No other change vs the proven-correct R1 source,
// so per-thread FP op order (and thus all values, incl. argmax ties) is preserved.

__device__ __forceinline__ void compute_partials(
    const float (&wA)[32], const float (&wB)[32],
    const float* __restrict__ tileA, const float* __restrict__ tileB,
    float* __restrict__ part, int q, int j)
{
#pragma unroll 2
    for (int b8 = 0; b8 < 8; ++b8) {
        const float4* pa = (const float4*)&tileA[b8*H_ + q*32];
        const float4* pb = (const float4*)&tileB[b8*H_ + q*32];
        float sa = 0.f, sb2 = 0.f;
#pragma unroll
        for (int kq = 0; kq < 8; ++kq) {
            float4 a4 = pa[kq];
            sa += wA[kq*4+0]*a4.x; sa += wA[kq*4+1]*a4.y;
            sa += wA[kq*4+2]*a4.z; sa += wA[kq*4+3]*a4.w;
            float4 b4 = pb[kq];
            sb2 += wB[kq*4+0]*b4.x; sb2 += wB[kq*4+1]*b4.y;
            sb2 += wB[kq*4+2]*b4.z; sb2 += wB[kq*4+3]*b4.w;
        }
        part[q*576 + j*9 + b8] = sa + sb2;   // j padded by 9 to spread banks
    }
}

__device__ __forceinline__ void head_for(
    int tt, const float* __restrict__ h1full, int b0, int js, int q, int j,
    const float* __restrict__ Wp, const float* __restrict__ bp,
    const float* __restrict__ Wb, const float* __restrict__ bb,
    float* __restrict__ out)
{
    // wave q handles batch b0+q; j-slice js handles output rows js and js+16 (row 18 = baseline)
    float4 hv = *(const float4*)&h1full[(b0 + q)*H_ + j*4];
    for (int aa = js; aa < 19; aa += 16) {
        float4 wv; float bias;
        if (aa < 18) { wv = *(const float4*)&Wp[aa*H_ + j*4]; bias = bp[aa]; }
        else         { wv = *(const float4*)&Wb[j*4];         bias = bb[0]; }
        float p = hv.x*wv.x + hv.y*wv.y + hv.z*wv.z + hv.w*wv.w;
#pragma unroll
        for (int s = 32; s; s >>= 1) p += __shfl_xor(p, s, 64);
        if (j == 0) {
            if (aa < 18) out[(size_t)(tt*B_ + b0 + q)*A_ + aa] = p + bias;
            else         out[OUT_BASE + tt*B_ + b0 + q]        = p + bias;
        }
    }
}

__global__ __launch_bounds__(512, 1) void lstm_scan(
    const float* __restrict__ x, const int* __restrict__ done,
    const float* __restrict__ h0in, const float* __restrict__ c0in,
    const float* __restrict__ w_ih, const float* __restrict__ w_hh,
    const float* __restrict__ b_ih, const float* __restrict__ b_hh,
    const float* __restrict__ Wp, const float* __restrict__ bp,
    const float* __restrict__ Wb, const float* __restrict__ bb,
    float* __restrict__ out, float* __restrict__ h0buf, float* __restrict__ h1buf)
{
    cg::grid_group grid = cg::this_grid();

    const int tid = threadIdx.x;
    const int wg  = blockIdx.x;
    const int js  = wg & 15;          // j-slice
    const int bs  = wg >> 4;          // batch-slice
    const int b0  = bs * 8;
    const int us  = js * 16;          // first h-unit of slice

    const int q = tid >> 6;           // wave id (k-chunk)
    const int j = tid & 63;           // lane = local gate row

    __shared__ __align__(16) float tileA[8*H_];
    __shared__ __align__(16) float tileB[8*H_];
    __shared__ __align__(16) float part[8*576];
    __shared__ __align__(16) float gates[64*8];
    __shared__ float biasS[2*64];
    __shared__ float cs[2*128];

    // ---- persistent weight fragments in VGPRs ----
    const int gate = j >> 4, uu = j & 15;
    const int grow = gate*H_ + us + uu;       // global gate row in [0,1024)
    float w0i[32], w0h[32], w1i[32], w1h[32];
    {
        const float* p = w_ih + (size_t)grow*H_ + q*32;
#pragma unroll
        for (int k = 0; k < 32; ++k) w0i[k] = p[k];
        p = w_hh + (size_t)grow*H_ + q*32;
#pragma unroll
        for (int k = 0; k < 32; ++k) w0h[k] = p[k];
        p = w_ih + (size_t)G4H*H_ + (size_t)grow*H_ + q*32;
#pragma unroll
        for (int k = 0; k < 32; ++k) w1i[k] = p[k];
        p = w_hh + (size_t)G4H*H_ + (size_t)grow*H_ + q*32;
#pragma unroll
        for (int k = 0; k < 32; ++k) w1h[k] = p[k];
    }

    // ---- init: combined bias, c-state, h buffers (parity 1) ----
    if (tid < 128) {
        int l = tid >> 6, r = tid & 63;
        int gr = (r >> 4)*H_ + us + (r & 15);
        biasS[tid] = b_ih[l*G4H + gr] + b_hh[l*G4H + gr];
    }
    if (tid < 256) {
        int l = tid >> 7, i = tid & 127;
        int u = i >> 3, b = i & 7;
        cs[tid] = c0in[l*B_*H_ + (b0 + b)*H_ + us + u];
    }
    for (int i = tid; i < 2*8*H_; i += 512) {          // copy h0 input into parity-1 bufs
        int l = i >> 11;
        int rem = i & 2047;                            // b*256+k within slice
        float v = h0in[l*B_*H_ + b0*H_ + rem];
        (l ? h1buf : h0buf)[B_*H_ + b0*H_ + rem] = v;
    }
    __threadfence();
    grid.sync();

    for (int t = 0; t < T_; ++t) {
        const int par = t & 1;
        const float* hprev0 = h0buf + (1 - par)*B_*H_;
        const float* hprev1 = h1buf + (1 - par)*B_*H_;
        float* hcur0 = h0buf + par*B_*H_;
        float* hcur1 = h1buf + par*B_*H_;

        const int sb = q;                               // staging batch = wave id
        const float nd = done[t*B_ + b0 + sb] ? 0.f : 1.f;
        const int kk = j * 4;

        // ======== phase 0 : layer 0 ========
        {
            float4 va = *(const float4*)&x[((size_t)t*B_ + b0 + sb)*H_ + kk];
            float4 vb = *(const float4*)&hprev0[(b0 + sb)*H_ + kk];
            vb.x *= nd; vb.y *= nd; vb.z *= nd; vb.w *= nd;
            *(float4*)&tileA[sb*H_ + kk] = va;
            *(float4*)&tileB[sb*H_ + kk] = vb;
        }
        __syncthreads();
        compute_partials(w0i, w0h, tileA, tileB, part, q, j);
        __syncthreads();
        {   // reduce 8 waves + bias
            int r = tid >> 3, b = tid & 7;
            float g = biasS[0*64 + r];
#pragma unroll
            for (int qq = 0; qq < 8; ++qq) g += part[qq*576 + r*9 + b];
            gates[r*8 + b] = g;
        }
        __syncthreads();
        if (tid < 128) {
            int u = tid >> 3, b = tid & 7;
            float gi = gates[(u)*8 + b],  gf = gates[(16+u)*8 + b];
            float gg = gates[(32+u)*8 + b], go = gates[(48+u)*8 + b];
            float ii = 1.f/(1.f + expf(-gi));
            float ff = 1.f/(1.f + expf(-gf));
            float g2 = tanhf(gg);
            float oo = 1.f/(1.f + expf(-go));
            float ndb = done[t*B_ + b0 + b] ? 0.f : 1.f;
            float c = ff*(cs[tid]*ndb) + ii*g2;
            float h = oo*tanhf(c);
            cs[tid] = c;
            hcur0[(b0 + b)*H_ + us + u] = h;
            if (t == T_-1) {
                out[OUT_HT + (b0 + b)*H_ + us + u] = h;
                out[OUT_CT + (b0 + b)*H_ + us + u] = c;
            }
        }
        __threadfence();
        grid.sync();                                    // h0(t) now visible everywhere

        // head for step t-1 (h1buf[1-par] is stable this step)
        if (t > 0) head_for(t - 1, hprev1, b0, js, q, j, Wp, bp, Wb, bb, out);

        // ======== phase 1 : layer 1 ========
        {
            float4 va = *(const float4*)&hcur0[(b0 + sb)*H_ + kk];   // fresh, unmasked
            float4 vb = *(const float4*)&hprev1[(b0 + sb)*H_ + kk];
            vb.x *= nd; vb.y *= nd; vb.z *= nd; vb.w *= nd;
            *(float4*)&tileA[sb*H_ + kk] = va;
            *(float4*)&tileB[sb*H_ + kk] = vb;
        }
        __syncthreads();
        compute_partials(w1i, w1h, tileA, tileB, part, q, j);
        __syncthreads();
        {
            int r = tid >> 3, b = tid & 7;
            float g = biasS[1*64 + r];
#pragma unroll
            for (int qq = 0; qq < 8; ++qq) g += part[qq*576 + r*9 + b];
            gates[r*8 + b] = g;
        }
        __syncthreads();
        if (tid < 128) {
            int u = tid >> 3, b = tid & 7;
            float gi = gates[(u)*8 + b],  gf = gates[(16+u)*8 + b];
            float gg = gates[(32+u)*8 + b], go = gates[(48+u)*8 + b];
            float ii = 1.f/(1.f + expf(-gi));
            float ff = 1.f/(1.f + expf(-gf));
            float g2 = tanhf(gg);
            float oo = 1.f/(1.f + expf(-go));
            float ndb = done[t*B_ + b0 + b] ? 0.f : 1.f;
            float c = ff*(cs[128 + tid]*ndb) + ii*g2;
            float h = oo*tanhf(c);
            cs[128 + tid] = c;
            hcur1[(b0 + b)*H_ + us + u] = h;
            if (t == T_-1) {
                out[OUT_HT + B_*H_ + (b0 + b)*H_ + us + u] = h;
                out[OUT_CT + B_*H_ + (b0 + b)*H_ + us + u] = c;
            }
        }
        __threadfence();
        grid.sync();                                    // h1(t) now visible everywhere
    }

    // head for the final step
    head_for(T_-1, h1buf + ((T_-1) & 1)*B_*H_, b0, js, q, j, Wp, bp, Wb, bb, out);
}

__global__ void argmax_head(const float* __restrict__ logits, float* __restrict__ out_act)
{
    int i = blockIdx.x*256 + threadIdx.x;
    if (i >= TB_) return;
    const float* lg = logits + (size_t)i*A_;
    float best = lg[0]; int bi = 0;
#pragma unroll
    for (int a = 1; a < A_; ++a) { float v = lg[a]; if (v > best) { best = v; bi = a; } }
    out_act[i] = (float)bi;
}

extern "C" void kernel_launch(void* const* d_in, const int* in_sizes, int n_in,
                              void* d_out, int out_size, void* d_ws, size_t ws_size,
                              hipStream_t stream)
{
    const float* x    = (const float*)d_in[0];
    const int*   done = (const int*)  d_in[1];
    const float* h0   = (const float*)d_in[2];
    const float* c0   = (const float*)d_in[3];
    const float* w_ih = (const float*)d_in[4];
    const float* w_hh = (const float*)d_in[5];
    const float* b_ih = (const float*)d_in[6];
    const float* b_hh = (const float*)d_in[7];
    const float* Wp   = (const float*)d_in[8];
    const float* bp   = (const float*)d_in[9];
    const float* Wb   = (const float*)d_in[10];
    const float* bb   = (const float*)d_in[11];
    float* out   = (float*)d_out;
    float* h0buf = (float*)d_ws;                 // [2][B][H]
    float* h1buf = h0buf + 2*B_*H_;              // [2][B][H]

    void* args[] = { (void*)&x, (void*)&done, (void*)&h0, (void*)&c0,
                     (void*)&w_ih, (void*)&w_hh, (void*)&b_ih, (void*)&b_hh,
                     (void*)&Wp, (void*)&bp, (void*)&Wb, (void*)&bb,
                     (void*)&out, (void*)&h0buf, (void*)&h1buf };
    hipLaunchCooperativeKernel((void*)lstm_scan, dim3(256), dim3(512), args, 0, stream);

    argmax_head<<<TB_/256, 256, 0, stream>>>(out, out + OUT_ACT);
}

// Round 5
// 69285.229 us; speedup vs baseline: 1.2738x; 1.2738x over previous
//
#include <hip/hip_runtime.h>
#include <hip/hip_cooperative_groups.h>
#include <math.h>

namespace cg = cooperative_groups;

#define T_  512
#define B_  128
#define H_  256
#define A_  18
#define G4H 1024          // 4*H
#define TB_ (T_*B_)       // 65536

// d_out layout (floats): [logits T*B*A][baseline T*B][action T*B][hT L*B*H][cT L*B*H]
#define OUT_BASE  (TB_*A_)
#define OUT_ACT   (OUT_BASE + TB_)
#define OUT_HT    (OUT_ACT + TB_)
#define OUT_CT    (OUT_HT + 2*B_*H_)

// WG tiling (R1-proven skeleton): 16 j-slices (16 h-units -> 64 gate rows/matrix)
// x 16 batch-slices (8 batches). 512 threads/WG, 256 WGs, 2 grid.syncs/step.
//
// ENGINE (new vs R1): weights are NOT register-persistent. R1/R4 hard evidence:
// 512-thr blocks pin VGPR_Count at 128 regardless of __launch_bounds__ arg 2
// (measured twice), so 128 floats/thread of weights ALWAYS spill -> 19.5 GB
// scratch fetch -> 86 ms. Instead weights (2 MB total, L2-resident per XCD)
// are streamed each phase as coalesced dwordx4 (~2.3K cyc/CU/phase at 56 B/cyc
// L2 BW, overlapped across 8 waves). Thread mapping: r4 = tid>>5 owns rows
// r4*4+e (4-row register blocking -> 4x fewer LDS tile reads than R1),
// kc = tid&31 owns float4 cols kc and kc+32 (bank-clean).

__device__ __forceinline__ void do_phase_engine(
    const float* __restrict__ wI, const float* __restrict__ wH,
    const float* __restrict__ tileA, const float* __restrict__ tileB,
    float* __restrict__ part, int r4, int kc, int us)
{
    // 4 rows' weight fragments for this phase: 16 coalesced dwordx4 from L2
    float4 wi[4][2], wh[4][2];
#pragma unroll
    for (int e = 0; e < 4; ++e) {
        int r = r4*4 + e;
        int grow = (r >> 4)*H_ + us + (r & 15);       // global gate row
        const float4* pi = (const float4*)(wI + (size_t)grow*H_);
        const float4* ph = (const float4*)(wH + (size_t)grow*H_);
        wi[e][0] = pi[kc]; wi[e][1] = pi[kc + 32];
        wh[e][0] = ph[kc]; wh[e][1] = ph[kc + 32];
    }
#pragma unroll
    for (int b = 0; b < 8; ++b) {
        const float4* pa = ((const float4*)tileA) + b*64;
        const float4* pb = ((const float4*)tileB) + b*64;
        float4 a1 = pa[kc], a2 = pa[kc + 32];
        float4 h1 = pb[kc], h2 = pb[kc + 32];
#pragma unroll
        for (int e = 0; e < 4; ++e) {
            float s;
            s  = a1.x*wi[e][0].x + a1.y*wi[e][0].y + a1.z*wi[e][0].z + a1.w*wi[e][0].w;
            s += a2.x*wi[e][1].x + a2.y*wi[e][1].y + a2.z*wi[e][1].z + a2.w*wi[e][1].w;
            s += h1.x*wh[e][0].x + h1.y*wh[e][0].y + h1.z*wh[e][0].z + h1.w*wh[e][0].w;
            s += h2.x*wh[e][1].x + h2.y*wh[e][1].y + h2.z*wh[e][1].z + h2.w*wh[e][1].w;
            // part[(row*8 + b)*36 + kc]: writer lanes (consecutive kc) conflict-free;
            // reader does 8 aligned float4 loads per (row,b). 36-pitch = 4-aligned.
            part[(((r4*4 + e)*8) + b)*36 + kc] = s;
        }
    }
}

__device__ __forceinline__ void head_for(
    int tt, const float* __restrict__ h1full, int b0, int js, int q, int j,
    const float* __restrict__ Wp, const float* __restrict__ bp,
    const float* __restrict__ Wb, const float* __restrict__ bb,
    float* __restrict__ out)
{
    // wave q handles batch b0+q; j-slice js handles output rows js and js+16 (row 18 = baseline)
    float4 hv = *(const float4*)&h1full[(b0 + q)*H_ + j*4];
    for (int aa = js; aa < 19; aa += 16) {
        float4 wv; float bias;
        if (aa < 18) { wv = *(const float4*)&Wp[aa*H_ + j*4]; bias = bp[aa]; }
        else         { wv = *(const float4*)&Wb[j*4];         bias = bb[0]; }
        float p = hv.x*wv.x + hv.y*wv.y + hv.z*wv.z + hv.w*wv.w;
#pragma unroll
        for (int s = 32; s; s >>= 1) p += __shfl_xor(p, s, 64);
        if (j == 0) {
            if (aa < 18) out[(size_t)(tt*B_ + b0 + q)*A_ + aa] = p + bias;
            else         out[OUT_BASE + tt*B_ + b0 + q]        = p + bias;
        }
    }
}

__global__ __launch_bounds__(512, 1) void lstm_scan(
    const float* __restrict__ x, const int* __restrict__ done,
    const float* __restrict__ h0in, const float* __restrict__ c0in,
    const float* __restrict__ w_ih, const float* __restrict__ w_hh,
    const float* __restrict__ b_ih, const float* __restrict__ b_hh,
    const float* __restrict__ Wp, const float* __restrict__ bp,
    const float* __restrict__ Wb, const float* __restrict__ bb,
    float* __restrict__ out, float* __restrict__ h0buf, float* __restrict__ h1buf)
{
    cg::grid_group grid = cg::this_grid();

    const int tid = threadIdx.x;
    const int wg  = blockIdx.x;
    const int js  = wg & 15;          // j-slice
    const int bs  = wg >> 4;          // batch-slice
    const int b0  = bs * 8;
    const int us  = js * 16;          // first h-unit of slice

    const int q = tid >> 6;           // wave id (staging batch / head batch)
    const int j = tid & 63;           // lane (staging/head column index)

    const int r4 = tid >> 5;          // engine: row-group (rows r4*4+e)
    const int kc = tid & 31;          // engine: k float4-chunk (kc, kc+32)

    __shared__ __align__(16) float tileA[8*H_];
    __shared__ __align__(16) float tileB[8*H_];
    __shared__ __align__(16) float part[64*8*36];     // 73728 B
    __shared__ __align__(16) float gates[64*8];
    __shared__ float biasS[2*64];
    __shared__ float cs[2*128];

    // ---- init: combined bias, c-state, h buffers (parity 1) ---- (R1 verbatim)
    if (tid < 128) {
        int l = tid >> 6, r = tid & 63;
        int gr = (r >> 4)*H_ + us + (r & 15);
        biasS[tid] = b_ih[l*G4H + gr] + b_hh[l*G4H + gr];
    }
    if (tid < 256) {
        int l = tid >> 7, i = tid & 127;
        int u = i >> 3, b = i & 7;
        cs[tid] = c0in[l*B_*H_ + (b0 + b)*H_ + us + u];
    }
    for (int i = tid; i < 2*8*H_; i += 512) {          // copy h0 input into parity-1 bufs
        int l = i >> 11;
        int rem = i & 2047;                            // b*256+k within slice
        float v = h0in[l*B_*H_ + b0*H_ + rem];
        (l ? h1buf : h0buf)[B_*H_ + b0*H_ + rem] = v;
    }
    __threadfence();
    grid.sync();

    const float* w_ih1 = w_ih + (size_t)G4H*H_;
    const float* w_hh1 = w_hh + (size_t)G4H*H_;

    for (int t = 0; t < T_; ++t) {
        const int par = t & 1;
        const float* hprev0 = h0buf + (1 - par)*B_*H_;
        const float* hprev1 = h1buf + (1 - par)*B_*H_;
        float* hcur0 = h0buf + par*B_*H_;
        float* hcur1 = h1buf + par*B_*H_;

        const int sb = q;                               // staging batch = wave id
        const float nd = done[t*B_ + b0 + sb] ? 0.f : 1.f;
        const int kk = j * 4;

        // ======== phase 0 : layer 0 ======== (staging R1 verbatim)
        {
            float4 va = *(const float4*)&x[((size_t)t*B_ + b0 + sb)*H_ + kk];
            float4 vb = *(const float4*)&hprev0[(b0 + sb)*H_ + kk];
            vb.x *= nd; vb.y *= nd; vb.z *= nd; vb.w *= nd;
            *(float4*)&tileA[sb*H_ + kk] = va;
            *(float4*)&tileB[sb*H_ + kk] = vb;
        }
        __syncthreads();
        do_phase_engine(w_ih, w_hh, tileA, tileB, part, r4, kc, us);
        __syncthreads();
        {   // reduce 32 k-chunks + bias: thread (rr = tid>>3, bb = tid&7)
            int rr = tid >> 3, bb = tid & 7;
            const float4* p4 = (const float4*)(part + (rr*8 + bb)*36);
            float4 s4 = p4[0];
#pragma unroll
            for (int c = 1; c < 8; ++c) {
                float4 v = p4[c];
                s4.x += v.x; s4.y += v.y; s4.z += v.z; s4.w += v.w;
            }
            gates[rr*8 + bb] = (s4.x + s4.y) + (s4.z + s4.w) + biasS[0*64 + rr];
        }
        __syncthreads();
        if (tid < 128) {    // cell update (R1 verbatim)
            int u = tid >> 3, b = tid & 7;
            float gi = gates[(u)*8 + b],  gf = gates[(16+u)*8 + b];
            float gg = gates[(32+u)*8 + b], go = gates[(48+u)*8 + b];
            float ii = 1.f/(1.f + expf(-gi));
            float ff = 1.f/(1.f + expf(-gf));
            float g2 = tanhf(gg);
            float oo = 1.f/(1.f + expf(-go));
            float ndb = done[t*B_ + b0 + b] ? 0.f : 1.f;
            float c = ff*(cs[tid]*ndb) + ii*g2;
            float h = oo*tanhf(c);
            cs[tid] = c;
            hcur0[(b0 + b)*H_ + us + u] = h;
            if (t == T_-1) {
                out[OUT_HT + (b0 + b)*H_ + us + u] = h;
                out[OUT_CT + (b0 + b)*H_ + us + u] = c;
            }
        }
        __threadfence();
        grid.sync();                                    // h0(t) now visible everywhere

        // head for step t-1 (h1buf[1-par] is stable this step)
        if (t > 0) head_for(t - 1, hprev1, b0, js, q, j, Wp, bp, Wb, bb, out);

        // ======== phase 1 : layer 1 ======== (staging R1 verbatim)
        {
            float4 va = *(const float4*)&hcur0[(b0 + sb)*H_ + kk];   // fresh, unmasked
            float4 vb = *(const float4*)&hprev1[(b0 + sb)*H_ + kk];
            vb.x *= nd; vb.y *= nd; vb.z *= nd; vb.w *= nd;
            *(float4*)&tileA[sb*H_ + kk] = va;
            *(float4*)&tileB[sb*H_ + kk] = vb;
        }
        __syncthreads();
        do_phase_engine(w_ih1, w_hh1, tileA, tileB, part, r4, kc, us);
        __syncthreads();
        {
            int rr = tid >> 3, bb = tid & 7;
            const float4* p4 = (const float4*)(part + (rr*8 + bb)*36);
            float4 s4 = p4[0];
#pragma unroll
            for (int c = 1; c < 8; ++c) {
                float4 v = p4[c];
                s4.x += v.x; s4.y += v.y; s4.z += v.z; s4.w += v.w;
            }
            gates[rr*8 + bb] = (s4.x + s4.y) + (s4.z + s4.w) + biasS[1*64 + rr];
        }
        __syncthreads();
        if (tid < 128) {    // cell update (R1 verbatim)
            int u = tid >> 3, b = tid & 7;
            float gi = gates[(u)*8 + b],  gf = gates[(16+u)*8 + b];
            float gg = gates[(32+u)*8 + b], go = gates[(48+u)*8 + b];
            float ii = 1.f/(1.f + expf(-gi));
            float ff = 1.f/(1.f + expf(-gf));
            float g2 = tanhf(gg);
            float oo = 1.f/(1.f + expf(-go));
            float ndb = done[t*B_ + b0 + b] ? 0.f : 1.f;
            float c = ff*(cs[128 + tid]*ndb) + ii*g2;
            float h = oo*tanhf(c);
            cs[128 + tid] = c;
            hcur1[(b0 + b)*H_ + us + u] = h;
            if (t == T_-1) {
                out[OUT_HT + B_*H_ + (b0 + b)*H_ + us + u] = h;
                out[OUT_CT + B_*H_ + (b0 + b)*H_ + us + u] = c;
            }
        }
        __threadfence();
        grid.sync();                                    // h1(t) now visible everywhere
    }

    // head for the final step
    head_for(T_-1, h1buf + ((T_-1) & 1)*B_*H_, b0, js, q, j, Wp, bp, Wb, bb, out);
}

__global__ void argmax_head(const float* __restrict__ logits, float* __restrict__ out_act)
{
    int i = blockIdx.x*256 + threadIdx.x;
    if (i >= TB_) return;
    const float* lg = logits + (size_t)i*A_;
    float best = lg[0]; int bi = 0;
#pragma unroll
    for (int a = 1; a < A_; ++a) { float v = lg[a]; if (v > best) { best = v; bi = a; } }
    out_act[i] = (float)bi;
}

extern "C" void kernel_launch(void* const* d_in, const int* in_sizes, int n_in,
                              void* d_out, int out_size, void* d_ws, size_t ws_size,
                              hipStream_t stream)
{
    const float* x    = (const float*)d_in[0];
    const int*   done = (const int*)  d_in[1];
    const float* h0   = (const float*)d_in[2];
    const float* c0   = (const float*)d_in[3];
    const float* w_ih = (const float*)d_in[4];
    const float* w_hh = (const float*)d_in[5];
    const float* b_ih = (const float*)d_in[6];
    const float* b_hh = (const float*)d_in[7];
    const float* Wp   = (const float*)d_in[8];
    const float* bp   = (const float*)d_in[9];
    const float* Wb   = (const float*)d_in[10];
    const float* bb   = (const float*)d_in[11];
    float* out   = (float*)d_out;
    float* h0buf = (float*)d_ws;                 // [2][B][H]
    float* h1buf = h0buf + 2*B_*H_;              // [2][B][H]

    void* args[] = { (void*)&x, (void*)&done, (void*)&h0, (void*)&c0,
                     (void*)&w_ih, (void*)&w_hh, (void*)&b_ih, (void*)&b_hh,
                     (void*)&Wp, (void*)&bp, (void*)&Wb, (void*)&bb,
                     (void*)&out, (void*)&h0buf, (void*)&h1buf };
    hipLaunchCooperativeKernel((void*)lstm_scan, dim3(256), dim3(512), args, 0, stream);

    argmax_head<<<TB_/256, 256, 0, stream>>>(out, out + OUT_ACT);
}

// Round 6
// 23016.235 us; speedup vs baseline: 3.8346x; 3.0103x over previous
//
#include <hip/hip_runtime.h>
#include <math.h>

#define T_  512
#define B_  128
#define H_  256
#define A_  18
#define G4H 1024          // 4*H
#define TB_ (T_*B_)       // 65536

// d_out layout (floats): [logits T*B*A][baseline T*B][action T*B][hT 2*B*H][cT 2*B*H]
#define OUT_BASE  (TB_*A_)
#define OUT_ACT   (OUT_BASE + TB_)
#define OUT_HT    (OUT_ACT + TB_)
#define OUT_CT    (OUT_HT + 2*B_*H_)

#define PP 66   // part pitch (floats): 66%32=2 -> reduce reads ~2-way (free); 8B-aligned for float2

// ZERO-SYNC DESIGN (R5 evidence: VALUBusy 3.5%, ~65 us per grid.sync x 1024 = the
// entire 67 ms stall; cross-XCD barrier fences are structural, not tunable).
// 128 WGs, one per batch chain: the whole T=512 x 2-layer recurrence + head +
// argmax runs inside one WG. No cooperative launch, no grid sync, no fences,
// no workspace. h/c state in LDS/registers. Weights (4 MB) stream from the
// XCD-local L2 every step, perfectly coalesced: one wave-instr reads one full
// 1 KB weight row (64 lanes x float4). Cost: 4 MB/step at ~64 B/cyc/CU L2 BW
// ~= 27 us/step -> ~14 ms; VALU (~7 us) and LDS (~5 us) hide under it.

__global__ __launch_bounds__(1024, 1) void lstm_batch(
    const float* __restrict__ x, const int* __restrict__ done,
    const float* __restrict__ h0in, const float* __restrict__ c0in,
    const float* __restrict__ w_ih, const float* __restrict__ w_hh,
    const float* __restrict__ b_ih, const float* __restrict__ b_hh,
    const float* __restrict__ Wp, const float* __restrict__ bp,
    const float* __restrict__ Wb, const float* __restrict__ bb,
    float* __restrict__ out)
{
    const int tid  = threadIdx.x;
    const int b    = blockIdx.x;          // batch owned by this WG
    const int w    = tid >> 6;            // wave 0..15
    const int lane = tid & 63;            // lane = k-chunk (4 floats at 4*lane)

    __shared__ __align__(16) float part[512*PP];   // 135168 B: per-row lane partials
    __shared__ __align__(16) float xv[H_];
    __shared__ __align__(16) float h0v[H_];
    __shared__ __align__(16) float h1v[H_];
    __shared__ __align__(16) float gates[G4H];
    __shared__ __align__(16) float biasC[2*G4H];
    // total LDS = 135168+1024*3+4096+8192 = 150528 B < 160 KiB

    // ---- init: state + combined bias ----
    float c0r = 0.f, c1r = 0.f;
    if (tid < H_) {
        h0v[tid] = h0in[0*B_*H_ + b*H_ + tid];
        h1v[tid] = h0in[1*B_*H_ + b*H_ + tid];
        c0r = c0in[0*B_*H_ + b*H_ + tid];
        c1r = c0in[1*B_*H_ + b*H_ + tid];
    }
    for (int i = tid; i < 2*G4H; i += 1024) biasC[i] = b_ih[i] + b_hh[i];
    __syncthreads();

    for (int t = 0; t < T_; ++t) {
        // ---- stage x(t) + apply done-reset to h,c ----
        if (tid < H_) {
            float nd = done[t*B_ + b] ? 0.f : 1.f;
            xv[tid] = x[((size_t)t*B_ + b)*H_ + tid];
            h0v[tid] *= nd;
            h1v[tid] *= nd;
            c0r *= nd;  c1r *= nd;
        }
        __syncthreads();

        for (int layer = 0; layer < 2; ++layer) {
            const float* wI  = w_ih + (size_t)layer*G4H*H_;
            const float* wH  = w_hh + (size_t)layer*G4H*H_;
            const float* inv = layer ? h0v : xv;    // layer input (fresh, unmasked for l=1)
            const float* hv  = layer ? h1v : h0v;   // recurrent input (masked)

            for (int half = 0; half < 2; ++half) {
                const int R0 = half * 512;          // row block [R0, R0+512)
                float4 a4 = ((const float4*)inv)[lane];
                float4 h4 = ((const float4*)hv)[lane];
                const int rbase = R0 + w*32;
#pragma unroll 8
                for (int rr = 0; rr < 32; ++rr) {   // one coalesced 1 KB row per instr
                    int r = rbase + rr;
                    float4 wi4 = ((const float4*)(wI + (size_t)r*H_))[lane];
                    float4 wh4 = ((const float4*)(wH + (size_t)r*H_))[lane];
                    float s = wi4.x*a4.x + wi4.y*a4.y + wi4.z*a4.z + wi4.w*a4.w
                            + wh4.x*h4.x + wh4.y*h4.y + wh4.z*h4.z + wh4.w*h4.w;
                    part[(w*32 + rr)*PP + lane] = s;    // lanes consecutive: 2-way, free
                }
                __syncthreads();
                if (tid < 512) {                    // reduce 64 lane-partials per row
                    const float2* p2 = (const float2*)(part + tid*PP);
                    float sx = 0.f, sy = 0.f;
#pragma unroll
                    for (int jj = 0; jj < 32; ++jj) { float2 v = p2[jj]; sx += v.x; sy += v.y; }
                    gates[R0 + tid] = sx + sy + biasC[layer*G4H + R0 + tid];
                }
                __syncthreads();
            }

            // ---- cell update (pytorch gate order i,f,g,o) ----
            if (tid < H_) {
                float gi = gates[tid],        gf = gates[H_ + tid];
                float gg = gates[2*H_ + tid], go = gates[3*H_ + tid];
                float ii = 1.f/(1.f + expf(-gi));
                float ff = 1.f/(1.f + expf(-gf));
                float gt = tanhf(gg);
                float oo = 1.f/(1.f + expf(-go));
                float& cr = layer ? c1r : c0r;      // c already nd-masked at stage
                cr = ff*cr + ii*gt;
                float h = oo*tanhf(cr);
                (layer ? h1v : h0v)[tid] = h;
            }
            __syncthreads();
        }

        // ---- head: 19 rows (18 policy + baseline), 16 k-chunks each ----
        if (tid < 304) {
            int a = tid >> 4, kc = tid & 15;
            const float4* wrow = (const float4*)((a < 18) ? (Wp + a*H_) : Wb);
            const float4* hv4  = (const float4*)h1v;
            float s = 0.f;
#pragma unroll
            for (int jj = 0; jj < 4; ++jj) {
                float4 wv = wrow[kc*4 + jj];
                float4 hh = hv4[kc*4 + jj];       // broadcast LDS reads
                s += wv.x*hh.x + wv.y*hh.y + wv.z*hh.z + wv.w*hh.w;
            }
            s += __shfl_xor(s, 1); s += __shfl_xor(s, 2);
            s += __shfl_xor(s, 4); s += __shfl_xor(s, 8);
            if (kc == 0) {
                if (a < 18) {
                    float v = s + bp[a];
                    out[((size_t)t*B_ + b)*A_ + a] = v;
                    gates[a] = v;                  // stash for argmax (gates free now)
                } else {
                    out[OUT_BASE + t*B_ + b] = s + bb[0];
                }
            }
        }
        __syncthreads();
        if (tid == 0) {                            // argmax (first-max ties, = np)
            float best = gates[0]; int bi = 0;
#pragma unroll
            for (int a = 1; a < A_; ++a) { float v = gates[a]; if (v > best) { best = v; bi = a; } }
            out[OUT_ACT + t*B_ + b] = (float)bi;
        }
        if (t == T_-1 && tid < H_) {
            out[OUT_HT + 0*B_*H_ + b*H_ + tid] = h0v[tid];
            out[OUT_HT + 1*B_*H_ + b*H_ + tid] = h1v[tid];
            out[OUT_CT + 0*B_*H_ + b*H_ + tid] = c0r;
            out[OUT_CT + 1*B_*H_ + b*H_ + tid] = c1r;
        }
        __syncthreads();   // protect h1v/gates before next step's stage overwrite
    }
}

extern "C" void kernel_launch(void* const* d_in, const int* in_sizes, int n_in,
                              void* d_out, int out_size, void* d_ws, size_t ws_size,
                              hipStream_t stream)
{
    const float* x    = (const float*)d_in[0];
    const int*   done = (const int*)  d_in[1];
    const float* h0   = (const float*)d_in[2];
    const float* c0   = (const float*)d_in[3];
    const float* w_ih = (const float*)d_in[4];
    const float* w_hh = (const float*)d_in[5];
    const float* b_ih = (const float*)d_in[6];
    const float* b_hh = (const float*)d_in[7];
    const float* Wp   = (const float*)d_in[8];
    const float* bp   = (const float*)d_in[9];
    const float* Wb   = (const float*)d_in[10];
    const float* bb   = (const float*)d_in[11];
    float* out = (float*)d_out;

    lstm_batch<<<dim3(B_), dim3(1024), 0, stream>>>(
        x, done, h0, c0, w_ih, w_hh, b_ih, b_hh, Wp, bp, Wb, bb, out);
}